// Round 2
// baseline (210.312 us; speedup 1.0000x reference)
//
#include <hip/hip_runtime.h>

#define K_DIM 4096
#define N_DIM 4096

typedef int v4i __attribute__((ext_vector_type(4)));

__device__ __forceinline__ void gload_lds16(const void* g, void* l) {
  __builtin_amdgcn_global_load_lds(
      (const __attribute__((address_space(1))) void*)g,
      (__attribute__((address_space(3))) void*)l, 16, 0, 0);
}

__device__ __forceinline__ int pack4(int4 w) {
  return (w.x & 0xff) | ((w.y & 0xff) << 8) | ((w.z & 0xff) << 16) | (w.w << 24);
}

// int32 -> int8 pack, 16 elements per thread
__global__ __launch_bounds__(256) void pack_kernel(const int* __restrict__ src,
                                                   int4* __restrict__ dst, int n16) {
  int i = blockIdx.x * 256 + threadIdx.x;
  if (i >= n16) return;
  const int4* s = (const int4*)src + (size_t)i * 4;
  int4 w0 = s[0], w1 = s[1], w2 = s[2], w3 = s[3];
  int4 r;
  r.x = pack4(w0); r.y = pack4(w1); r.z = pack4(w2); r.w = pack4(w3);
  dst[i] = r;
}

// 128x128 tile, BK=128 (bytes), 4 waves 2x2, mfma_i32_16x16x64_i8.
// LDS layout: linear [row][chunk] with data pre-swizzled at the SOURCE:
// LDS(row, c) holds global chunk (c ^ (row&7)); ds_read applies the same XOR.
template <bool PACKED>
__global__ __launch_bounds__(256, 2) void gemm_i8(
    const void* __restrict__ Asrc, const void* __restrict__ Bsrc,
    const int* __restrict__ bias, const float* __restrict__ pa,
    const float* __restrict__ pb, int* __restrict__ out, int gridM) {
  __shared__ __align__(16) char As[128 * 128];
  __shared__ __align__(16) char Bs[128 * 128];

  const int tid = threadIdx.x;
  const int wid = tid >> 6;
  const int lane = tid & 63;

  // XCD-aware bijective swizzle (nwg % 8 == 0)
  const int nwg = gridM * 32;
  const int cpx = nwg >> 3;
  const int flat = blockIdx.x;
  const int wg = (flat & 7) * cpx + (flat >> 3);
  const int br = wg >> 5;   // 0..gridM-1
  const int bn = wg & 31;   // 0..31

  const int rowi = tid >> 3;                      // 0..31 (row within 32-row issue)
  const int swzc = (tid & 7) ^ (rowi & 7);        // pre-swizzled source chunk

  v4i acc[4][4];
  {
    v4i z = {0, 0, 0, 0};
#pragma unroll
    for (int mi = 0; mi < 4; ++mi)
#pragma unroll
      for (int ni = 0; ni < 4; ++ni) acc[mi][ni] = z;
  }

  const int wr = wid >> 1;
  const int wc = wid & 1;

  // staging source base (PACKED path): per-lane global address, linear LDS dest
  const char* Ag = (const char*)Asrc + (size_t)(br * 128 + rowi) * K_DIM + swzc * 16;
  const char* Bg = (const char*)Bsrc + (size_t)(bn * 128 + rowi) * K_DIM + swzc * 16;

  for (int ks = 0; ks < K_DIM / 128; ++ks) {
    if constexpr (PACKED) {
      const char* a0 = Ag + ks * 128;
      const char* b0 = Bg + ks * 128;
#pragma unroll
      for (int is = 0; is < 4; ++is) {
        gload_lds16(a0 + (size_t)is * 32 * K_DIM, &As[is * 4096 + wid * 1024]);
        gload_lds16(b0 + (size_t)is * 32 * K_DIM, &Bs[is * 4096 + wid * 1024]);
      }
    } else {
      const int* Ai = (const int*)Asrc;
      const int* Bi = (const int*)Bsrc;
#pragma unroll
      for (int is = 0; is < 4; ++is) {
        {
          const int4* p = (const int4*)(Ai + (size_t)(br * 128 + is * 32 + rowi) * K_DIM +
                                        ks * 128 + swzc * 16);
          int4 w0 = p[0], w1 = p[1], w2 = p[2], w3 = p[3];
          v4i r = {pack4(w0), pack4(w1), pack4(w2), pack4(w3)};
          *(v4i*)&As[is * 4096 + tid * 16] = r;
        }
        {
          const int4* p = (const int4*)(Bi + (size_t)(bn * 128 + is * 32 + rowi) * K_DIM +
                                        ks * 128 + swzc * 16);
          int4 w0 = p[0], w1 = p[1], w2 = p[2], w3 = p[3];
          v4i r = {pack4(w0), pack4(w1), pack4(w2), pack4(w3)};
          *(v4i*)&Bs[is * 4096 + tid * 16] = r;
        }
      }
    }
    __syncthreads();

#pragma unroll
    for (int ksub = 0; ksub < 2; ++ksub) {
      const int g = lane >> 4;
      const int kk = ksub * 4 + g;
      v4i af[4], bf[4];
#pragma unroll
      for (int mi = 0; mi < 4; ++mi) {
        const int r = wr * 64 + mi * 16 + (lane & 15);
        af[mi] = *(const v4i*)&As[r * 128 + ((kk ^ (r & 7)) * 16)];
      }
#pragma unroll
      for (int ni = 0; ni < 4; ++ni) {
        const int r = wc * 64 + ni * 16 + (lane & 15);
        bf[ni] = *(const v4i*)&Bs[r * 128 + ((kk ^ (r & 7)) * 16)];
      }
#pragma unroll
      for (int mi = 0; mi < 4; ++mi)
#pragma unroll
        for (int ni = 0; ni < 4; ++ni)
          acc[mi][ni] =
              __builtin_amdgcn_mfma_i32_16x16x64_i8(af[mi], bf[ni], acc[mi][ni], 0, 0, 0);
    }
    __syncthreads();
  }

  // epilogue: y = round(alpha*acc + beta*bias), clamp to int8 range,
  // write as INT32 (harness reads integer outputs as int32)
  const float alpha = *pa;
  const float beta = *pb;
  const int col = lane & 15;
  const int rg = lane >> 4;
#pragma unroll
  for (int ni = 0; ni < 4; ++ni) {
    const int n = bn * 128 + wc * 64 + ni * 16 + col;
    const float bb = __fmul_rn(beta, (float)bias[n]);
#pragma unroll
    for (int mi = 0; mi < 4; ++mi) {
#pragma unroll
      for (int j = 0; j < 4; ++j) {
        const int m = br * 128 + wr * 64 + mi * 16 + rg * 4 + j;
        float y = __fadd_rn(__fmul_rn(alpha, (float)acc[mi][ni][j]), bb);
        y = rintf(y);
        y = fminf(127.f, fmaxf(-128.f, y));
        out[(size_t)m * N_DIM + n] = (int)y;
      }
    }
  }
}

extern "C" void kernel_launch(void* const* d_in, const int* in_sizes, int n_in,
                              void* d_out, int out_size, void* d_ws, size_t ws_size,
                              hipStream_t stream) {
  const int* x = (const int*)d_in[0];       // [M,K] int8 values in int32
  const int* w = (const int*)d_in[1];       // [N,K] int8 values in int32
  const int* bias = (const int*)d_in[2];    // [N] int8 values in int32
  const float* pa = (const float*)d_in[3];  // alpha
  const float* pb = (const float*)d_in[4];  // beta
  int* out = (int*)d_out;

  const int M = in_sizes[0] / K_DIM;  // 8192
  const int gridM = M / 128;          // 64
  const size_t xBytes = (size_t)M * K_DIM;
  const size_t wBytes = (size_t)N_DIM * K_DIM;

  if (ws_size >= xBytes + wBytes) {
    char* xp = (char*)d_ws;
    char* wp = xp + xBytes;
    const int n16x = (int)(xBytes / 16);
    const int n16w = (int)(wBytes / 16);
    pack_kernel<<<(n16x + 255) / 256, 256, 0, stream>>>(x, (int4*)xp, n16x);
    pack_kernel<<<(n16w + 255) / 256, 256, 0, stream>>>(w, (int4*)wp, n16w);
    gemm_i8<true><<<gridM * 32, 256, 0, stream>>>(xp, wp, bias, pa, pb, out, gridM);
  } else {
    gemm_i8<false><<<gridM * 32, 256, 0, stream>>>(x, w, bias, pa, pb, out, gridM);
  }
}

// Round 3
// 196.873 us; speedup vs baseline: 1.0683x; 1.0683x over previous
//
#include <hip/hip_runtime.h>

#define K_DIM 4096
#define N_DIM 4096
#define NT (K_DIM / 64)  // 64 K-tiles, 64 bytes deep each

typedef int v4i __attribute__((ext_vector_type(4)));

__device__ __forceinline__ void gload_lds16(const void* g, void* l) {
  __builtin_amdgcn_global_load_lds(
      (const __attribute__((address_space(1))) void*)g,
      (__attribute__((address_space(3))) void*)l, 16, 0, 0);
}

__device__ __forceinline__ int pack4(int4 w) {
  return (w.x & 0xff) | ((w.y & 0xff) << 8) | ((w.z & 0xff) << 16) | (w.w << 24);
}

// int32 -> int8 pack, 64 elements per thread
__global__ __launch_bounds__(256) void pack_kernel(const int* __restrict__ src,
                                                   int4* __restrict__ dst, int n16) {
  int i = blockIdx.x * 256 + threadIdx.x;
  if (i >= n16) return;
  const int4* s = (const int4*)src + (size_t)i * 4;
  int4 w0 = s[0], w1 = s[1], w2 = s[2], w3 = s[3];
  int4 r;
  r.x = pack4(w0); r.y = pack4(w1); r.z = pack4(w2); r.w = pack4(w3);
  dst[i] = r;
}

// 256x256 tile, BK=64 bytes, 8 waves (2M x 4N), mfma_i32_16x16x64_i8.
// 4-slot circular LDS (A: 4x16KB, B: 4x16KB = 128 KB), staged 3 K-tiles
// ahead with counted vmcnt(8) at K-tile boundaries (never drains to 0 in
// the main loop). Raw s_barrier (no compiler vmcnt(0) drain).
// LDS swizzle: slot(r,c) holds global 16B-chunk c ^ ((r>>1)&3); the
// inverse permutation is applied on the global SOURCE address (linear
// LDS dest required by global_load_lds), same XOR applied on ds_read.
__global__ __launch_bounds__(512, 2) void gemm256(
    const char* __restrict__ Ap, const char* __restrict__ Bp,
    const int* __restrict__ bias, const float* __restrict__ pa,
    const float* __restrict__ pb, int* __restrict__ out) {
  extern __shared__ __align__(16) char lds[];  // 131072 bytes

  const int tid = threadIdx.x;
  const int wid = tid >> 6;
  const int lane = tid & 63;

  // XCD-aware bijective swizzle (nwg = 512, % 8 == 0)
  const int nwg = gridDim.x;
  const int cpx = nwg >> 3;
  const int flat = blockIdx.x;
  const int wg = (flat & 7) * cpx + (flat >> 3);
  const int br = wg >> 4;  // 0..31 (M/256)
  const int bn = wg & 15;  // 0..15 (N/256)

  const int wr = wid >> 2;   // 0..1  -> M half (128 rows)
  const int wcol = wid & 3;  // 0..3  -> N quarter (64 cols)

  // --- staging addressing (per-lane global, wave-uniform LDS base) ---
  const int srow = tid >> 2;                         // 0..127
  const int schunk = (tid & 3) ^ ((tid >> 3) & 3);   // inverse-swizzled source chunk
  const char* aSrc = Ap + (size_t)(br * 256 + srow) * K_DIM + schunk * 16;
  const char* bSrc = Bp + (size_t)(bn * 256 + srow) * K_DIM + schunk * 16;
  char* const ldsA = lds;            // + slot*16384 + u*8192 + wid*1024
  char* const ldsB = lds + 65536;

  auto stageA = [&](int kt) {
    const char* s = aSrc + kt * 64;
    char* d = ldsA + (kt & 3) * 16384 + wid * 1024;
    gload_lds16(s, d);
    gload_lds16(s + (size_t)128 * K_DIM, d + 8192);
  };
  auto stageB = [&](int kt) {
    const char* s = bSrc + kt * 64;
    char* d = ldsB + (kt & 3) * 16384 + wid * 1024;
    gload_lds16(s, d);
    gload_lds16(s + (size_t)128 * K_DIM, d + 8192);
  };

  // --- fragment read addressing ---
  const int lrow = lane & 15;
  const int fchunk = lane >> 4;                         // g: which 16B of the 64B K-slice
  const int rchunk = fchunk ^ ((lrow >> 1) & 3);        // swizzled slot chunk
  const int aOff = (wr * 128 + lrow) * 64 + rchunk * 16;          // + mi*1024 + slot*16384
  const int bOff = 65536 + (wcol * 64 + lrow) * 64 + rchunk * 16; // + ni*1024 + slot*16384

  v4i acc[8][4];
  {
    v4i z = {0, 0, 0, 0};
#pragma unroll
    for (int mi = 0; mi < 8; ++mi)
#pragma unroll
      for (int ni = 0; ni < 4; ++ni) acc[mi][ni] = z;
  }

  // prologue: stage K-tiles 0,1,2 (12 loads outstanding)
  stageA(0); stageB(0);
  stageA(1); stageB(1);
  stageA(2); stageB(2);

  for (int kt = 0; kt < NT; ++kt) {
    // boundary: my share of S(kt) landed; barrier -> everyone's share landed
    if (kt < NT - 2)
      asm volatile("s_waitcnt vmcnt(8)" ::: "memory");
    else if (kt == NT - 2)
      asm volatile("s_waitcnt vmcnt(4)" ::: "memory");
    else
      asm volatile("s_waitcnt vmcnt(0)" ::: "memory");
    __builtin_amdgcn_s_barrier();

    const int sb = (kt & 3) * 16384;

    // ---- phase A: quadrant mi 0..3 ----
    v4i af[4], bf[4];
#pragma unroll
    for (int mi = 0; mi < 4; ++mi) af[mi] = *(const v4i*)&lds[sb + aOff + mi * 1024];
#pragma unroll
    for (int ni = 0; ni < 4; ++ni) bf[ni] = *(const v4i*)&lds[sb + bOff + ni * 1024];
    if (kt < NT - 3) stageA(kt + 3);  // writes slot (kt-1)&3: reads completed pre-boundary
    __builtin_amdgcn_s_barrier();
    __builtin_amdgcn_s_setprio(1);
#pragma unroll
    for (int mi = 0; mi < 4; ++mi)
#pragma unroll
      for (int ni = 0; ni < 4; ++ni)
        acc[mi][ni] =
            __builtin_amdgcn_mfma_i32_16x16x64_i8(af[mi], bf[ni], acc[mi][ni], 0, 0, 0);
    __builtin_amdgcn_s_setprio(0);

    // ---- phase B: quadrant mi 4..7 (bf reused) ----
    v4i af2[4];
#pragma unroll
    for (int mi = 0; mi < 4; ++mi) af2[mi] = *(const v4i*)&lds[sb + aOff + (mi + 4) * 1024];
    if (kt < NT - 3) stageB(kt + 3);
    __builtin_amdgcn_s_barrier();
    __builtin_amdgcn_s_setprio(1);
#pragma unroll
    for (int mi = 0; mi < 4; ++mi)
#pragma unroll
      for (int ni = 0; ni < 4; ++ni)
        acc[mi + 4][ni] =
            __builtin_amdgcn_mfma_i32_16x16x64_i8(af2[mi], bf[ni], acc[mi + 4][ni], 0, 0, 0);
    __builtin_amdgcn_s_setprio(0);
  }

  // epilogue: y = round(alpha*acc + beta*bias), clamp, write int32
  const float alpha = *pa;
  const float beta = *pb;
  const int col = lane & 15;
  const int rg = lane >> 4;
#pragma unroll
  for (int ni = 0; ni < 4; ++ni) {
    const int n = bn * 256 + wcol * 64 + ni * 16 + col;
    const float bb = __fmul_rn(beta, (float)bias[n]);
#pragma unroll
    for (int mi = 0; mi < 8; ++mi) {
#pragma unroll
      for (int j = 0; j < 4; ++j) {
        const int m = br * 256 + wr * 128 + mi * 16 + rg * 4 + j;
        float y = __fadd_rn(__fmul_rn(alpha, (float)acc[mi][ni][j]), bb);
        y = rintf(y);
        y = fminf(127.f, fmaxf(-128.f, y));
        out[(size_t)m * N_DIM + n] = (int)y;
      }
    }
  }
}

extern "C" void kernel_launch(void* const* d_in, const int* in_sizes, int n_in,
                              void* d_out, int out_size, void* d_ws, size_t ws_size,
                              hipStream_t stream) {
  const int* x = (const int*)d_in[0];       // [M,K] int8 values in int32
  const int* w = (const int*)d_in[1];       // [N,K] int8 values in int32
  const int* bias = (const int*)d_in[2];    // [N] int8 values in int32
  const float* pa = (const float*)d_in[3];  // alpha
  const float* pb = (const float*)d_in[4];  // beta
  int* out = (int*)d_out;

  const int M = in_sizes[0] / K_DIM;  // 8192
  const size_t xBytes = (size_t)M * K_DIM;
  const size_t wBytes = (size_t)N_DIM * K_DIM;

  char* xp = (char*)d_ws;
  char* wp = xp + xBytes;
  const int n16x = (int)(xBytes / 16);
  const int n16w = (int)(wBytes / 16);
  pack_kernel<<<(n16x + 255) / 256, 256, 0, stream>>>(x, (int4*)xp, n16x);
  pack_kernel<<<(n16w + 255) / 256, 256, 0, stream>>>(w, (int4*)wp, n16w);

  const int nwg = (M / 256) * (N_DIM / 256);  // 32*16 = 512
  hipFuncSetAttribute((const void*)gemm256,
                      hipFuncAttributeMaxDynamicSharedMemorySize, 131072);
  gemm256<<<nwg, 512, 131072, stream>>>(xp, wp, bias, pa, pb, out);
}